// Round 3
// baseline (233.763 us; speedup 1.0000x reference)
//
#include <hip/hip_runtime.h>
#include <hip/hip_fp16.h>

#define NN 80000
#define NE 1280000
#define F  64
#define BSH 9                        // 512 nodes per bucket
#define NB  157                      // ceil(NN / 512)
#define CAP 12288                    // per-bucket ebuf capacity (avg 8153)
#define EPB 5120                     // edges per partition block (128 B runs)
#define EPT 10                       // EPB / 512
#define PBLK (NE / EPB)              // 250

typedef _Float16 half_t;
typedef _Float16 half8 __attribute__((ext_vector_type(8)));
typedef float f32x4 __attribute__((ext_vector_type(4)));
typedef unsigned int uint_t;

__device__ __forceinline__ float2 h2f2(uint_t u) {
    __half2 h = *(__half2*)&u;
    return __half22float2(h);
}

__device__ __forceinline__ int ld_src(const int* __restrict__ idx, int e, int is64) {
    return is64 ? idx[2 * e] : idx[e];
}
__device__ __forceinline__ int ld_dst(const int* __restrict__ idx, int e, int is64) {
    return is64 ? idx[2 * NE + 2 * e] : idx[NE + e];
}

// ---------------------------------------------------------------------------
// Pass 1 (512 threads): partition edges into NB dst-buckets via LDS staging
// (cache-granular global writes, ~32-edge/128 B runs).
// ebuf[b*CAP + j] = (dstoff<<17) | src. Inline int64-vs-int32 sniff.
// ---------------------------------------------------------------------------
__global__ __launch_bounds__(512) void partition_kernel(
        const int* __restrict__ idx,
        int* __restrict__ bcur, int* __restrict__ ebuf) {
    __shared__ int cnt[NB];
    __shared__ int lbase[NB];
    __shared__ int gbase[NB];
    __shared__ int lds_val[EPB];
    __shared__ int lds_gaddr[EPB];
    __shared__ int is64_s;
    int tid = threadIdx.x;
    if (tid == 0) is64_s = 1;
    if (tid < NB) cnt[tid] = 0;
    __syncthreads();
    if (idx[2 * tid + 1] != 0) is64_s = 0;   // benign same-value race
    __syncthreads();
    int is64 = is64_s;
    int e0 = blockIdx.x * EPB;
    int val[EPT], br[EPT];
    #pragma unroll
    for (int j = 0; j < EPT; ++j) {
        int e = e0 + j * 512 + tid;
        int s = ld_src(idx, e, is64);
        int d = ld_dst(idx, e, is64);
        int b = d >> BSH;
        val[j] = ((d & ((1 << BSH) - 1)) << 17) | s;
        int r = atomicAdd(&cnt[b], 1);       // rank within (block, bucket)
        br[j] = (b << 13) | r;               // r < 5120 < 2^13
    }
    __syncthreads();
    if (tid < 64) {
        int carry = 0;
        for (int base = 0; base < NB; base += 64) {
            int i2 = base + tid;
            int v = (i2 < NB) ? cnt[i2] : 0;
            int incl = v;
            #pragma unroll
            for (int d2 = 1; d2 < 64; d2 <<= 1) {
                int t = __shfl_up(incl, d2, 64);
                if (tid >= d2) incl += t;
            }
            if (i2 < NB) lbase[i2] = carry + incl - v;
            carry += __shfl(incl, 63);
        }
    } else if (tid - 64 < NB) {
        int b = tid - 64;
        gbase[b] = atomicAdd(&bcur[b], cnt[b]);
    }
    __syncthreads();
    #pragma unroll
    for (int j = 0; j < EPT; ++j) {
        int b = br[j] >> 13, r = br[j] & 8191;
        int slot = lbase[b] + r;
        int g = gbase[b] + r;
        lds_val[slot]   = val[j];
        lds_gaddr[slot] = (g < CAP) ? (b * CAP + g) : -1;   // overflow guard
    }
    __syncthreads();
    for (int i = tid; i < EPB; i += 512) {
        int a = lds_gaddr[i];
        if (a >= 0) ebuf[a] = lds_val[i];    // ~32-edge (128 B) contiguous runs
    }
}

// ---------------------------------------------------------------------------
// Pass 2 (1024 threads): per-bucket LDS counting sort -> final CSR edata +
// row_ptr + dinv, with prescale folded in (y0 = fp16(X * dinv)).
// ---------------------------------------------------------------------------
__global__ __launch_bounds__(1024) void bucket_sort_kernel(
        const int* __restrict__ bcur, const int* __restrict__ ebuf,
        const float* __restrict__ X,
        int* __restrict__ edata, int* __restrict__ row_ptr,
        float* __restrict__ dinv, half_t* __restrict__ y0) {
    __shared__ int cnt[512];
    __shared__ int off[512];
    __shared__ int lds_out[CAP];
    __shared__ int ebase_s;
    int b = blockIdx.x, tid = threadIdx.x;
    if (tid < 512) cnt[tid] = 0;
    if (tid < 64) {        // ebase = sum of min(bcur[j],CAP) for j<b
        int carry = 0;
        for (int base = 0; base < NB; base += 64) {
            int i2 = base + tid;
            int v = (i2 < NB) ? min(bcur[i2], CAP) : 0;
            int incl = v;
            #pragma unroll
            for (int d2 = 1; d2 < 64; d2 <<= 1) {
                int t = __shfl_up(incl, d2, 64);
                if (tid >= d2) incl += t;
            }
            if (i2 == b) ebase_s = carry + incl - v;
            carry += __shfl(incl, 63);
        }
    }
    __syncthreads();
    int bcnt = min(bcur[b], CAP);
    int ebase = ebase_s;
    const int* src = ebuf + b * CAP;
    for (int i = tid; i < bcnt; i += 1024)
        atomicAdd(&cnt[src[i] >> 17], 1);
    __syncthreads();
    if (tid < 64) {        // exclusive scan of 512 counters
        int carry = 0;
        #pragma unroll
        for (int base = 0; base < 512; base += 64) {
            int v = cnt[base + tid];
            int incl = v;
            #pragma unroll
            for (int d2 = 1; d2 < 64; d2 <<= 1) {
                int t = __shfl_up(incl, d2, 64);
                if (tid >= d2) incl += t;
            }
            off[base + tid] = carry + incl - v;
            carry += __shfl(incl, 63);
        }
    }
    __syncthreads();
    int n0 = b << BSH;
    if (tid < 512) {
        int n = n0 + tid;
        if (n < NN) {
            row_ptr[n] = ebase + off[tid];
            dinv[n] = rsqrtf((float)cnt[tid] + 1.f);
        } else if (n == NN) {
            row_ptr[NN] = ebase + off[tid];
        }
    }
    __syncthreads();
    for (int i = tid; i < bcnt; i += 1024) {
        int w = src[i];
        int pos = atomicAdd(&off[w >> 17], 1);
        lds_out[pos] = w & 0x1FFFF;
    }
    __syncthreads();
    for (int i = tid; i < bcnt; i += 1024)
        edata[ebase + i] = lds_out[i];
    // folded prescale: y0 = fp16(X * dinv) for this bucket's 512 rows.
    for (int i = tid; i < (512 << 4); i += 1024) {
        int r = i >> 4, qq = i & 15;
        int n = n0 + r;
        if (n < NN) {
            float c = rsqrtf((float)cnt[r] + 1.f);
            float4 v = ((const float4*)(X + (size_t)n * F))[qq];
            half_t h[4] = { (half_t)(v.x * c), (half_t)(v.y * c),
                            (half_t)(v.z * c), (half_t)(v.w * c) };
            ((uint2*)(y0 + (size_t)n * F))[qq] = *(uint2*)h;
        }
    }
}

// --------------------------- gather helpers --------------------------------
__device__ __forceinline__ uint4 ldrow(const half_t* __restrict__ y, int s, int fl) {
    return ((const uint4*)(y + (size_t)s * F))[fl];
}

__device__ __forceinline__ void acc8(float* a, const uint4& u, float m) {
    float2 f0 = h2f2(u.x), f1 = h2f2(u.y);
    float2 f2 = h2f2(u.z), f3 = h2f2(u.w);
    a[0] = fmaf(m, f0.x, a[0]); a[1] = fmaf(m, f0.y, a[1]);
    a[2] = fmaf(m, f1.x, a[2]); a[3] = fmaf(m, f1.y, a[3]);
    a[4] = fmaf(m, f2.x, a[4]); a[5] = fmaf(m, f2.y, a[5]);
    a[6] = fmaf(m, f3.x, a[6]); a[7] = fmaf(m, f3.y, a[7]);
}

// ---------------------------------------------------------------------------
// Fused gather + MFMA GEMM per layer — node-parallel gather.
// Block = 512 threads / 8 waves / 64 nodes. Lane mapping: lane = g*8 + q,
// group g (8 lanes) owns node rbase+g; lane q owns features [q*8, q*8+8).
// All 8 nodes of a wave gather CONCURRENTLY: per chunk, each group loads 8
// edge indices coalesced (lane q -> edata[p0+k8+q]), then 8 iterations of
// {1 shfl broadcast + 1 row load + masked acc8}. No cross-lane reduce, no
// divergent epilogue, no masked 32-slot tail => ~3 dynamic instr/edge vs
// ~13 before. Degree divergence costs iters = max(deg of 8 nodes) ~ 22.
// ---------------------------------------------------------------------------
template <int RELU, int LAST>
__global__ __launch_bounds__(512, 6) void fused_layer(
        const half_t* __restrict__ y,
        const int* __restrict__ edata, const int* __restrict__ row_ptr,
        const float* __restrict__ dinv,
        const float* __restrict__ W, const float* __restrict__ bias,
        half_t* __restrict__ out_h, float* __restrict__ out_f32) {
    __shared__ __align__(16) half_t Wt[64][72];   // W^T fp16, padded
    __shared__ __align__(16) half_t xt[64][72];   // gathered A tile
    int tid = threadIdx.x;
    // stage W through registers: loads issue now, LDS write after gather
    float wreg[8];
    #pragma unroll
    for (int i = 0; i < 8; ++i) wreg[i] = W[tid + i * 512];
    int wv = tid >> 6, lane = tid & 63;
    int g = lane >> 3;          // node group 0..7
    int q = lane & 7;           // uint4 feature index within 128 B row
    int gbase = lane & 56;      // first lane of this group
    int n0 = blockIdx.x * 64;   // grid = NN/64 exact
    int rbase = wv * 8;
    int node = n0 + rbase + g;
    int p0 = row_ptr[node], p1 = row_ptr[node + 1];
    int deg = p1 - p0;
    // wave-uniform loop bound: max degree over the wave's 8 groups
    int dmax = deg;
    dmax = max(dmax, __shfl_xor(dmax, 8));
    dmax = max(dmax, __shfl_xor(dmax, 16));
    dmax = max(dmax, __shfl_xor(dmax, 32));
    uint4 us = ldrow(y, node, q);            // self row
    float a[8];
    {
        float2 f0 = h2f2(us.x), f1 = h2f2(us.y);
        float2 f2 = h2f2(us.z), f3 = h2f2(us.w);
        a[0] = f0.x; a[1] = f0.y; a[2] = f1.x; a[3] = f1.y;
        a[4] = f2.x; a[5] = f2.y; a[6] = f3.x; a[7] = f3.y;
    }
    #pragma unroll 1
    for (int k8 = 0; k8 < dmax; k8 += 8) {
        int ei = p0 + k8 + q;                // this lane's prefetch slot
        ei = min(ei, p1 - 1); ei = max(ei, 0);
        int e = edata[ei];                   // 8 indices per group, coalesced
        #pragma unroll
        for (int k = 0; k < 8; ++k) {
            int s = __shfl(e, gbase | k);    // broadcast edge k to the group
            uint4 u = ldrow(y, s, q);
            float m = (k8 + k < deg) ? 1.f : 0.f;
            acc8(a, u, m);
        }
    }
    // epilogue: every lane writes its 16 B of the A tile — no divergence
    float dv = rsqrtf((float)deg + 1.f);
    half_t h[8] = { (half_t)(dv * a[0]), (half_t)(dv * a[1]),
                    (half_t)(dv * a[2]), (half_t)(dv * a[3]),
                    (half_t)(dv * a[4]), (half_t)(dv * a[5]),
                    (half_t)(dv * a[6]), (half_t)(dv * a[7]) };
    *(uint4*)&xt[rbase + g][q * 8] = *(uint4*)h;
    // commit W^T to LDS
    #pragma unroll
    for (int i = 0; i < 8; ++i) {
        int i2 = tid + i * 512;              // i2 = k*64 + n
        Wt[i2 & 63][i2 >> 6] = (half_t)wreg[i];
    }
    __syncthreads();
    // MFMA: wave wv -> row-tile (wv&3), col-tiles (wv>>2)*2 + {0,1}
    int m = lane & 15, q4 = lane >> 4;
    int rt = (wv & 3) * 16;
    int ct0 = (wv >> 2) * 2;
    const half_t* arow = &xt[rt + m][q4 * 8];
    half8 A0 = *(const half8*)arow;
    half8 A1 = *(const half8*)(arow + 32);
    float dvr[4];
    if (!LAST) {
        #pragma unroll
        for (int r = 0; r < 4; ++r) dvr[r] = dinv[n0 + rt + q4 * 4 + r];
    }
    #pragma unroll
    for (int c2 = 0; c2 < 2; ++c2) {
        int ct = (ct0 + c2) * 16;
        const half_t* brow = &Wt[ct + m][q4 * 8];
        half8 B0 = *(const half8*)brow;
        half8 B1 = *(const half8*)(brow + 32);
        f32x4 c = {0.f, 0.f, 0.f, 0.f};
        c = __builtin_amdgcn_mfma_f32_16x16x32_f16(A0, B0, c, 0, 0, 0);
        c = __builtin_amdgcn_mfma_f32_16x16x32_f16(A1, B1, c, 0, 0, 0);
        float bv = bias[ct + m];                   // col = ct*16 + (lane&15)
        #pragma unroll
        for (int r = 0; r < 4; ++r) {
            int row = n0 + rt + q4 * 4 + r;        // C/D: row = quad*4 + reg
            float v = c[r] + bv;
            if (RELU) v = fmaxf(v, 0.f);
            int col = ct + m;
            if (LAST) out_f32[(size_t)row * F + col] = v;
            else      out_h[(size_t)row * F + col] = (half_t)(v * dvr[r]);
        }
    }
}

extern "C" void kernel_launch(void* const* d_in, const int* in_sizes, int n_in,
                              void* d_out, int out_size, void* d_ws, size_t ws_size,
                              hipStream_t stream) {
    const float* X  = (const float*)d_in[0];
    const int*  idx = (const int*)d_in[1];
    const float* W1 = (const float*)d_in[2];
    const float* b1 = (const float*)d_in[3];
    const float* W2 = (const float*)d_in[4];
    const float* b2 = (const float*)d_in[5];
    const float* W3 = (const float*)d_in[6];
    const float* b3 = (const float*)d_in[7];
    float* out = (float*)d_out;

    char* ws = (char*)d_ws;
    int*    bcur    = (int*)(ws + 256);                 // NB ints
    int*    row_ptr = (int*)(ws + 1024);                // NN+1 ints
    float*  dinv    = (float*)(ws + 321280);            // NN floats
    int*    edata   = (int*)(ws + 641536);              // NE ints (final CSR)
    half_t* ybufA   = (half_t*)(ws + 5761536);          // [NN,64] fp16
    half_t* ybufB   = (half_t*)(ws + 16001536);         // [NN,64] fp16
    int*    ebuf    = (int*)(ws + 26241536);            // NB*CAP ints (7.7 MB)
    // total ws use ~34 MB

    hipMemsetAsync(bcur, 0, NB * sizeof(int), stream);
    partition_kernel<<<PBLK, 512, 0, stream>>>(idx, bcur, ebuf);
    bucket_sort_kernel<<<NB, 1024, 0, stream>>>(bcur, ebuf, X, edata, row_ptr, dinv, ybufA);

    const int fBlocks = NN / 64;      // 1250

    // layer 1: y1 = fp16(dinv*relu(agg(ybufA)@W1+b1)) -> ybufB
    fused_layer<1, 0><<<fBlocks, 512, 0, stream>>>(ybufA, edata, row_ptr, dinv, W1, b1, ybufB, nullptr);
    // layer 2
    fused_layer<1, 0><<<fBlocks, 512, 0, stream>>>(ybufB, edata, row_ptr, dinv, W2, b2, ybufA, nullptr);
    // layer 3: fp32 output, no relu / no scale
    fused_layer<0, 1><<<fBlocks, 512, 0, stream>>>(ybufA, edata, row_ptr, dinv, W3, b3, nullptr, out);
}

// Round 5
// 216.232 us; speedup vs baseline: 1.0811x; 1.0811x over previous
//
#include <hip/hip_runtime.h>
#include <hip/hip_fp16.h>

#define NN 80000
#define NE 1280000
#define F  64
#define BSH 9                        // 512 nodes per bucket
#define NB  157                      // ceil(NN / 512)
#define CAP 12288                    // per-bucket ebuf capacity (avg 8153)
#define EPB 5120                     // edges per partition block (128 B runs)
#define EPT 10                       // EPB / 512
#define PBLK (NE / EPB)              // 250

typedef _Float16 half_t;
typedef _Float16 half8 __attribute__((ext_vector_type(8)));
typedef float f32x4 __attribute__((ext_vector_type(4)));
typedef unsigned int uint_t;

__device__ __forceinline__ float2 h2f2(uint_t u) {
    __half2 h = *(__half2*)&u;
    return __half22float2(h);
}

__device__ __forceinline__ int ld_src(const int* __restrict__ idx, int e, int is64) {
    return is64 ? idx[2 * e] : idx[e];
}
__device__ __forceinline__ int ld_dst(const int* __restrict__ idx, int e, int is64) {
    return is64 ? idx[2 * NE + 2 * e] : idx[NE + e];
}

// ---------------------------------------------------------------------------
// Pass 1 (512 threads): partition edges into NB dst-buckets via LDS staging
// (cache-granular global writes, ~32-edge/128 B runs).
// ebuf[b*CAP + j] = (dstoff<<17) | src. Inline int64-vs-int32 sniff.
// ---------------------------------------------------------------------------
__global__ __launch_bounds__(512) void partition_kernel(
        const int* __restrict__ idx,
        int* __restrict__ bcur, int* __restrict__ ebuf) {
    __shared__ int cnt[NB];
    __shared__ int lbase[NB];
    __shared__ int gbase[NB];
    __shared__ int lds_val[EPB];
    __shared__ int lds_gaddr[EPB];
    __shared__ int is64_s;
    int tid = threadIdx.x;
    if (tid == 0) is64_s = 1;
    if (tid < NB) cnt[tid] = 0;
    __syncthreads();
    if (idx[2 * tid + 1] != 0) is64_s = 0;   // benign same-value race
    __syncthreads();
    int is64 = is64_s;
    int e0 = blockIdx.x * EPB;
    int val[EPT], br[EPT];
    #pragma unroll
    for (int j = 0; j < EPT; ++j) {
        int e = e0 + j * 512 + tid;
        int s = ld_src(idx, e, is64);
        int d = ld_dst(idx, e, is64);
        int b = d >> BSH;
        val[j] = ((d & ((1 << BSH) - 1)) << 17) | s;
        int r = atomicAdd(&cnt[b], 1);       // rank within (block, bucket)
        br[j] = (b << 13) | r;               // r < 5120 < 2^13
    }
    __syncthreads();
    if (tid < 64) {
        int carry = 0;
        for (int base = 0; base < NB; base += 64) {
            int i2 = base + tid;
            int v = (i2 < NB) ? cnt[i2] : 0;
            int incl = v;
            #pragma unroll
            for (int d2 = 1; d2 < 64; d2 <<= 1) {
                int t = __shfl_up(incl, d2, 64);
                if (tid >= d2) incl += t;
            }
            if (i2 < NB) lbase[i2] = carry + incl - v;
            carry += __shfl(incl, 63);
        }
    } else if (tid - 64 < NB) {
        int b = tid - 64;
        gbase[b] = atomicAdd(&bcur[b], cnt[b]);
    }
    __syncthreads();
    #pragma unroll
    for (int j = 0; j < EPT; ++j) {
        int b = br[j] >> 13, r = br[j] & 8191;
        int slot = lbase[b] + r;
        int g = gbase[b] + r;
        lds_val[slot]   = val[j];
        lds_gaddr[slot] = (g < CAP) ? (b * CAP + g) : -1;   // overflow guard
    }
    __syncthreads();
    for (int i = tid; i < EPB; i += 512) {
        int a = lds_gaddr[i];
        if (a >= 0) ebuf[a] = lds_val[i];    // ~32-edge (128 B) contiguous runs
    }
}

// ---------------------------------------------------------------------------
// Pass 2 (1024 threads): per-bucket LDS counting sort -> final CSR edata +
// row_ptr + dinv, with prescale folded in (y0 = fp16(X * dinv)).
// ---------------------------------------------------------------------------
__global__ __launch_bounds__(1024) void bucket_sort_kernel(
        const int* __restrict__ bcur, const int* __restrict__ ebuf,
        const float* __restrict__ X,
        int* __restrict__ edata, int* __restrict__ row_ptr,
        float* __restrict__ dinv, half_t* __restrict__ y0) {
    __shared__ int cnt[512];
    __shared__ int off[512];
    __shared__ int lds_out[CAP];
    __shared__ int ebase_s;
    int b = blockIdx.x, tid = threadIdx.x;
    if (tid < 512) cnt[tid] = 0;
    if (tid < 64) {        // ebase = sum of min(bcur[j],CAP) for j<b
        int carry = 0;
        for (int base = 0; base < NB; base += 64) {
            int i2 = base + tid;
            int v = (i2 < NB) ? min(bcur[i2], CAP) : 0;
            int incl = v;
            #pragma unroll
            for (int d2 = 1; d2 < 64; d2 <<= 1) {
                int t = __shfl_up(incl, d2, 64);
                if (tid >= d2) incl += t;
            }
            if (i2 == b) ebase_s = carry + incl - v;
            carry += __shfl(incl, 63);
        }
    }
    __syncthreads();
    int bcnt = min(bcur[b], CAP);
    int ebase = ebase_s;
    const int* src = ebuf + b * CAP;
    for (int i = tid; i < bcnt; i += 1024)
        atomicAdd(&cnt[src[i] >> 17], 1);
    __syncthreads();
    if (tid < 64) {        // exclusive scan of 512 counters
        int carry = 0;
        #pragma unroll
        for (int base = 0; base < 512; base += 64) {
            int v = cnt[base + tid];
            int incl = v;
            #pragma unroll
            for (int d2 = 1; d2 < 64; d2 <<= 1) {
                int t = __shfl_up(incl, d2, 64);
                if (tid >= d2) incl += t;
            }
            off[base + tid] = carry + incl - v;
            carry += __shfl(incl, 63);
        }
    }
    __syncthreads();
    int n0 = b << BSH;
    if (tid < 512) {
        int n = n0 + tid;
        if (n < NN) {
            row_ptr[n] = ebase + off[tid];
            dinv[n] = rsqrtf((float)cnt[tid] + 1.f);
        } else if (n == NN) {
            row_ptr[NN] = ebase + off[tid];
        }
    }
    __syncthreads();
    for (int i = tid; i < bcnt; i += 1024) {
        int w = src[i];
        int pos = atomicAdd(&off[w >> 17], 1);
        lds_out[pos] = w & 0x1FFFF;
    }
    __syncthreads();
    for (int i = tid; i < bcnt; i += 1024)
        edata[ebase + i] = lds_out[i];
    // folded prescale: y0 = fp16(X * dinv) for this bucket's 512 rows.
    for (int i = tid; i < (512 << 4); i += 1024) {
        int r = i >> 4, qq = i & 15;
        int n = n0 + r;
        if (n < NN) {
            float c = rsqrtf((float)cnt[r] + 1.f);
            float4 v = ((const float4*)(X + (size_t)n * F))[qq];
            half_t h[4] = { (half_t)(v.x * c), (half_t)(v.y * c),
                            (half_t)(v.z * c), (half_t)(v.w * c) };
            ((uint2*)(y0 + (size_t)n * F))[qq] = *(uint2*)h;
        }
    }
}

// --------------------------- gather helpers --------------------------------
__device__ __forceinline__ uint4 ldrow(const half_t* __restrict__ y, int s, int fl) {
    return ((const uint4*)(y + (size_t)s * F))[fl];
}

__device__ __forceinline__ void acc8(float* a, const uint4& u, float m) {
    float2 f0 = h2f2(u.x), f1 = h2f2(u.y);
    float2 f2 = h2f2(u.z), f3 = h2f2(u.w);
    a[0] = fmaf(m, f0.x, a[0]); a[1] = fmaf(m, f0.y, a[1]);
    a[2] = fmaf(m, f1.x, a[2]); a[3] = fmaf(m, f1.y, a[3]);
    a[4] = fmaf(m, f2.x, a[4]); a[5] = fmaf(m, f2.y, a[5]);
    a[6] = fmaf(m, f3.x, a[6]); a[7] = fmaf(m, f3.y, a[7]);
}

// ---------------------------------------------------------------------------
// Fused gather + MFMA GEMM per layer — node-parallel gather, max-TLP/MLP.
// Block = 256 threads / 4 waves / 32 nodes (grid 2500). Lane = g*8 + q:
// group g owns node rbase+g, lane q owns features [q*8, q*8+8).
// __launch_bounds__(256, 6): VGPR<=~84 (no spill risk) -> up to 24 waves/CU.
// Chunk pipeline: next chunk's edata load (clamped, branch-free) issues
// before current chunk's accumulates; row loads issued 4+4 so ~9-10 loads
// are in flight per wave. W goes to LDS up front (no live wreg).
// ---------------------------------------------------------------------------
template <int RELU, int LAST>
__global__ __launch_bounds__(256, 6) void fused_layer(
        const half_t* __restrict__ y,
        const int* __restrict__ edata, const int* __restrict__ row_ptr,
        const float* __restrict__ dinv,
        const float* __restrict__ W, const float* __restrict__ bias,
        half_t* __restrict__ out_h, float* __restrict__ out_f32) {
    __shared__ __align__(16) half_t Wt[64][72];   // W^T fp16, padded (9216 B)
    __shared__ __align__(16) half_t xt[32][72];   // gathered A tile (4608 B)
    int tid = threadIdx.x;
    // W^T -> LDS immediately (2500 blocks share W: L2/L3-resident, cheap)
    for (int i = tid; i < 4096; i += 256)
        Wt[i & 63][i >> 6] = (half_t)W[i];
    int wv = tid >> 6, lane = tid & 63;
    int g = lane >> 3;          // node group 0..7
    int q = lane & 7;           // uint4 feature index within 128 B row
    int gbase = lane & 56;      // first lane of this group
    int n0 = blockIdx.x * 32;   // grid = NN/32 exact
    int rbase = wv * 8;
    int node = n0 + rbase + g;
    int p0 = row_ptr[node], p1 = row_ptr[node + 1];
    int deg = p1 - p0;
    // wave-uniform loop bound: max degree over the wave's 8 groups
    int dmax = deg;
    dmax = max(dmax, __shfl_xor(dmax, 8));
    dmax = max(dmax, __shfl_xor(dmax, 16));
    dmax = max(dmax, __shfl_xor(dmax, 32));
    uint4 us = ldrow(y, node, q);            // self row
    float a[8];
    {
        float2 f0 = h2f2(us.x), f1 = h2f2(us.y);
        float2 f2 = h2f2(us.z), f3 = h2f2(us.w);
        a[0] = f0.x; a[1] = f0.y; a[2] = f1.x; a[3] = f1.y;
        a[4] = f2.x; a[5] = f2.y; a[6] = f3.x; a[7] = f3.y;
    }
    // prime chunk 0's edge indices (clamped, branch-free)
    int ei = p0 + q;
    ei = min(ei, p1 - 1); ei = max(ei, 0);
    int e = edata[ei];
    #pragma unroll 1
    for (int k8 = 0; k8 < dmax; k8 += 8) {
        // prefetch next chunk's indices (clamped dup -> L1 hit when past end)
        int ein = p0 + k8 + 8 + q;
        ein = min(ein, p1 - 1); ein = max(ein, 0);
        int e_nxt = edata[ein];
        // issue 8 row loads (shfl feeds address directly; 4+4 batches)
        uint4 u0[4], u1[4];
        #pragma unroll
        for (int k = 0; k < 4; ++k) u0[k] = ldrow(y, __shfl(e, gbase | k), q);
        #pragma unroll
        for (int k = 0; k < 4; ++k) u1[k] = ldrow(y, __shfl(e, gbase | (4 + k)), q);
        #pragma unroll
        for (int k = 0; k < 4; ++k) acc8(a, u0[k], (k8 + k < deg) ? 1.f : 0.f);
        #pragma unroll
        for (int k = 0; k < 4; ++k) acc8(a, u1[k], (k8 + 4 + k < deg) ? 1.f : 0.f);
        e = e_nxt;
    }
    // epilogue: every lane writes its 16 B of the A tile — no divergence
    float dv = rsqrtf((float)deg + 1.f);
    half_t h[8] = { (half_t)(dv * a[0]), (half_t)(dv * a[1]),
                    (half_t)(dv * a[2]), (half_t)(dv * a[3]),
                    (half_t)(dv * a[4]), (half_t)(dv * a[5]),
                    (half_t)(dv * a[6]), (half_t)(dv * a[7]) };
    *(uint4*)&xt[rbase + g][q * 8] = *(uint4*)h;
    __syncthreads();
    // MFMA: wave wv -> row-tile (wv&1), col-tiles (wv>>1)*2 + {0,1}
    int m = lane & 15, q4 = lane >> 4;
    int rt = (wv & 1) * 16;
    int ct0 = (wv >> 1) * 2;
    const half_t* arow = &xt[rt + m][q4 * 8];
    half8 A0 = *(const half8*)arow;
    half8 A1 = *(const half8*)(arow + 32);
    float dvr[4];
    if (!LAST) {
        #pragma unroll
        for (int r = 0; r < 4; ++r) dvr[r] = dinv[n0 + rt + q4 * 4 + r];
    }
    #pragma unroll
    for (int c2 = 0; c2 < 2; ++c2) {
        int ct = (ct0 + c2) * 16;
        const half_t* brow = &Wt[ct + m][q4 * 8];
        half8 B0 = *(const half8*)brow;
        half8 B1 = *(const half8*)(brow + 32);
        f32x4 c = {0.f, 0.f, 0.f, 0.f};
        c = __builtin_amdgcn_mfma_f32_16x16x32_f16(A0, B0, c, 0, 0, 0);
        c = __builtin_amdgcn_mfma_f32_16x16x32_f16(A1, B1, c, 0, 0, 0);
        float bv = bias[ct + m];                   // col = ct*16 + (lane&15)
        #pragma unroll
        for (int r = 0; r < 4; ++r) {
            int row = n0 + rt + q4 * 4 + r;        // C/D: row = quad*4 + reg
            float v = c[r] + bv;
            if (RELU) v = fmaxf(v, 0.f);
            int col = ct + m;
            if (LAST) out_f32[(size_t)row * F + col] = v;
            else      out_h[(size_t)row * F + col] = (half_t)(v * dvr[r]);
        }
    }
}

extern "C" void kernel_launch(void* const* d_in, const int* in_sizes, int n_in,
                              void* d_out, int out_size, void* d_ws, size_t ws_size,
                              hipStream_t stream) {
    const float* X  = (const float*)d_in[0];
    const int*  idx = (const int*)d_in[1];
    const float* W1 = (const float*)d_in[2];
    const float* b1 = (const float*)d_in[3];
    const float* W2 = (const float*)d_in[4];
    const float* b2 = (const float*)d_in[5];
    const float* W3 = (const float*)d_in[6];
    const float* b3 = (const float*)d_in[7];
    float* out = (float*)d_out;

    char* ws = (char*)d_ws;
    int*    bcur    = (int*)(ws + 256);                 // NB ints
    int*    row_ptr = (int*)(ws + 1024);                // NN+1 ints
    float*  dinv    = (float*)(ws + 321280);            // NN floats
    int*    edata   = (int*)(ws + 641536);              // NE ints (final CSR)
    half_t* ybufA   = (half_t*)(ws + 5761536);          // [NN,64] fp16
    half_t* ybufB   = (half_t*)(ws + 16001536);         // [NN,64] fp16
    int*    ebuf    = (int*)(ws + 26241536);            // NB*CAP ints (7.7 MB)
    // total ws use ~34 MB

    hipMemsetAsync(bcur, 0, NB * sizeof(int), stream);
    partition_kernel<<<PBLK, 512, 0, stream>>>(idx, bcur, ebuf);
    bucket_sort_kernel<<<NB, 1024, 0, stream>>>(bcur, ebuf, X, edata, row_ptr, dinv, ybufA);

    const int fBlocks = NN / 32;      // 2500

    // layer 1: y1 = fp16(dinv*relu(agg(ybufA)@W1+b1)) -> ybufB
    fused_layer<1, 0><<<fBlocks, 256, 0, stream>>>(ybufA, edata, row_ptr, dinv, W1, b1, ybufB, nullptr);
    // layer 2
    fused_layer<1, 0><<<fBlocks, 256, 0, stream>>>(ybufB, edata, row_ptr, dinv, W2, b2, ybufA, nullptr);
    // layer 3: fp32 output, no relu / no scale
    fused_layer<0, 1><<<fBlocks, 256, 0, stream>>>(ybufA, edata, row_ptr, dinv, W3, b3, nullptr, out);
}

// Round 6
// 212.953 us; speedup vs baseline: 1.0977x; 1.0154x over previous
//
#include <hip/hip_runtime.h>
#include <hip/hip_fp16.h>

#define NN 80000
#define NE 1280000
#define F  64
#define BSH 8                        // 256 nodes per bucket
#define NB  313                      // ceil(NN / 256)
#define CAP 6144                     // per-bucket ebuf capacity (avg ~4089)
#define EPB 5120                     // edges per partition block
#define EPT 10                       // EPB / 512
#define PBLK (NE / EPB)              // 250

typedef _Float16 half_t;
typedef _Float16 half8 __attribute__((ext_vector_type(8)));
typedef float f32x4 __attribute__((ext_vector_type(4)));
typedef unsigned int uint_t;

__device__ __forceinline__ float2 h2f2(uint_t u) {
    __half2 h = *(__half2*)&u;
    return __half22float2(h);
}

__device__ __forceinline__ int ld_src(const int* __restrict__ idx, int e, int is64) {
    return is64 ? idx[2 * e] : idx[e];
}
__device__ __forceinline__ int ld_dst(const int* __restrict__ idx, int e, int is64) {
    return is64 ? idx[2 * NE + 2 * e] : idx[NE + e];
}

// ---------------------------------------------------------------------------
// Pass 1 (512 threads): partition edges into NB dst-buckets via LDS staging
// (~16-edge / 64 B runs). ebuf[b*CAP + j] = (dstoff<<17) | src.
// ---------------------------------------------------------------------------
__global__ __launch_bounds__(512) void partition_kernel(
        const int* __restrict__ idx,
        int* __restrict__ bcur, int* __restrict__ ebuf) {
    __shared__ int cnt[NB];
    __shared__ int lbase[NB];
    __shared__ int gbase[NB];
    __shared__ int lds_val[EPB];
    __shared__ int lds_gaddr[EPB];
    __shared__ int is64_s;
    int tid = threadIdx.x;
    if (tid == 0) is64_s = 1;
    if (tid < NB) cnt[tid] = 0;
    __syncthreads();
    if (idx[2 * tid + 1] != 0) is64_s = 0;   // benign same-value race
    __syncthreads();
    int is64 = is64_s;
    int e0 = blockIdx.x * EPB;
    int val[EPT], br[EPT];
    #pragma unroll
    for (int j = 0; j < EPT; ++j) {
        int e = e0 + j * 512 + tid;
        int s = ld_src(idx, e, is64);
        int d = ld_dst(idx, e, is64);
        int b = d >> BSH;
        val[j] = ((d & ((1 << BSH) - 1)) << 17) | s;
        int r = atomicAdd(&cnt[b], 1);       // rank within (block, bucket)
        br[j] = (b << 13) | r;               // b<313 (9b), r<5120 (13b)
    }
    __syncthreads();
    if (tid < 64) {
        int carry = 0;
        for (int base = 0; base < NB; base += 64) {
            int i2 = base + tid;
            int v = (i2 < NB) ? cnt[i2] : 0;
            int incl = v;
            #pragma unroll
            for (int d2 = 1; d2 < 64; d2 <<= 1) {
                int t = __shfl_up(incl, d2, 64);
                if (tid >= d2) incl += t;
            }
            if (i2 < NB) lbase[i2] = carry + incl - v;
            carry += __shfl(incl, 63);
        }
    } else if (tid - 64 < NB) {
        int b = tid - 64;
        gbase[b] = atomicAdd(&bcur[b], cnt[b]);
    }
    __syncthreads();
    #pragma unroll
    for (int j = 0; j < EPT; ++j) {
        int b = br[j] >> 13, r = br[j] & 8191;
        int slot = lbase[b] + r;
        int g = gbase[b] + r;
        lds_val[slot]   = val[j];
        lds_gaddr[slot] = (g < CAP) ? (b * CAP + g) : -1;   // overflow guard
    }
    __syncthreads();
    for (int i = tid; i < EPB; i += 512) {
        int a = lds_gaddr[i];
        if (a >= 0) ebuf[a] = lds_val[i];    // ~16-edge (64 B) contiguous runs
    }
}

// ---------------------------------------------------------------------------
// Pass 2 (512 threads, 313 blocks, ~27 KB LDS): per-bucket counting sort ->
// final CSR edata + row_ptr + dinv, with prescale folded in.
// Halved bucket size vs prior rev: 2x block count, 1/4 LDS -> better CU
// coverage and latency hiding for the same total work.
// ---------------------------------------------------------------------------
__global__ __launch_bounds__(512) void bucket_sort_kernel(
        const int* __restrict__ bcur, const int* __restrict__ ebuf,
        const float* __restrict__ X,
        int* __restrict__ edata, int* __restrict__ row_ptr,
        float* __restrict__ dinv, half_t* __restrict__ y0) {
    __shared__ int cnt[256];
    __shared__ int off[256];
    __shared__ int lds_out[CAP];
    __shared__ int ebase_s;
    int b = blockIdx.x, tid = threadIdx.x;
    if (tid < 256) cnt[tid] = 0;
    if (tid < 64) {        // ebase = sum of min(bcur[j],CAP) for j<b
        int carry = 0;
        for (int base = 0; base < NB; base += 64) {
            int i2 = base + tid;
            int v = (i2 < NB) ? min(bcur[i2], CAP) : 0;
            int incl = v;
            #pragma unroll
            for (int d2 = 1; d2 < 64; d2 <<= 1) {
                int t = __shfl_up(incl, d2, 64);
                if (tid >= d2) incl += t;
            }
            if (i2 == b) ebase_s = carry + incl - v;
            carry += __shfl(incl, 63);
        }
    }
    __syncthreads();
    int bcnt = min(bcur[b], CAP);
    int ebase = ebase_s;
    const int* src = ebuf + b * CAP;
    for (int i = tid; i < bcnt; i += 512)
        atomicAdd(&cnt[src[i] >> 17], 1);
    __syncthreads();
    if (tid < 64) {        // exclusive scan of 256 counters
        int carry = 0;
        #pragma unroll
        for (int base = 0; base < 256; base += 64) {
            int v = cnt[base + tid];
            int incl = v;
            #pragma unroll
            for (int d2 = 1; d2 < 64; d2 <<= 1) {
                int t = __shfl_up(incl, d2, 64);
                if (tid >= d2) incl += t;
            }
            off[base + tid] = carry + incl - v;
            carry += __shfl(incl, 63);
        }
    }
    __syncthreads();
    int n0 = b << BSH;
    if (tid < 256) {
        int n = n0 + tid;
        if (n < NN) {
            row_ptr[n] = ebase + off[tid];
            dinv[n] = rsqrtf((float)cnt[tid] + 1.f);
        } else if (n == NN) {
            row_ptr[NN] = ebase + off[tid];
        }
    }
    __syncthreads();
    for (int i = tid; i < bcnt; i += 512) {
        int w = src[i];
        int pos = atomicAdd(&off[w >> 17], 1);
        lds_out[pos] = w & 0x1FFFF;
    }
    __syncthreads();
    for (int i = tid; i < bcnt; i += 512)
        edata[ebase + i] = lds_out[i];
    // folded prescale: y0 = fp16(X * dinv) for this bucket's 256 rows.
    for (int i = tid; i < (256 << 4); i += 512) {
        int r = i >> 4, qq = i & 15;
        int n = n0 + r;
        if (n < NN) {
            float c = rsqrtf((float)cnt[r] + 1.f);
            float4 v = ((const float4*)(X + (size_t)n * F))[qq];
            half_t h[4] = { (half_t)(v.x * c), (half_t)(v.y * c),
                            (half_t)(v.z * c), (half_t)(v.w * c) };
            ((uint2*)(y0 + (size_t)n * F))[qq] = *(uint2*)h;
        }
    }
}

// --------------------------- gather helpers --------------------------------
__device__ __forceinline__ uint4 ldrow(const half_t* __restrict__ y, int s, int fl) {
    return ((const uint4*)(y + (size_t)s * F))[fl];
}

__device__ __forceinline__ void acc8(float* a, const uint4& u, float m) {
    float2 f0 = h2f2(u.x), f1 = h2f2(u.y);
    float2 f2 = h2f2(u.z), f3 = h2f2(u.w);
    a[0] = fmaf(m, f0.x, a[0]); a[1] = fmaf(m, f0.y, a[1]);
    a[2] = fmaf(m, f1.x, a[2]); a[3] = fmaf(m, f1.y, a[3]);
    a[4] = fmaf(m, f2.x, a[4]); a[5] = fmaf(m, f2.y, a[5]);
    a[6] = fmaf(m, f3.x, a[6]); a[7] = fmaf(m, f3.y, a[7]);
}

// ---------------------------------------------------------------------------
// Fused gather + MFMA GEMM per layer — node-parallel gather (unchanged R5).
// Block = 256 threads / 4 waves / 32 nodes (grid 2500).
// ---------------------------------------------------------------------------
template <int RELU, int LAST>
__global__ __launch_bounds__(256, 6) void fused_layer(
        const half_t* __restrict__ y,
        const int* __restrict__ edata, const int* __restrict__ row_ptr,
        const float* __restrict__ dinv,
        const float* __restrict__ W, const float* __restrict__ bias,
        half_t* __restrict__ out_h, float* __restrict__ out_f32) {
    __shared__ __align__(16) half_t Wt[64][72];   // W^T fp16, padded (9216 B)
    __shared__ __align__(16) half_t xt[32][72];   // gathered A tile (4608 B)
    int tid = threadIdx.x;
    for (int i = tid; i < 4096; i += 256)
        Wt[i & 63][i >> 6] = (half_t)W[i];
    int wv = tid >> 6, lane = tid & 63;
    int g = lane >> 3;          // node group 0..7
    int q = lane & 7;           // uint4 feature index within 128 B row
    int gbase = lane & 56;      // first lane of this group
    int n0 = blockIdx.x * 32;   // grid = NN/32 exact
    int rbase = wv * 8;
    int node = n0 + rbase + g;
    int p0 = row_ptr[node], p1 = row_ptr[node + 1];
    int deg = p1 - p0;
    // wave-uniform loop bound: max degree over the wave's 8 groups
    int dmax = deg;
    dmax = max(dmax, __shfl_xor(dmax, 8));
    dmax = max(dmax, __shfl_xor(dmax, 16));
    dmax = max(dmax, __shfl_xor(dmax, 32));
    uint4 us = ldrow(y, node, q);            // self row
    float a[8];
    {
        float2 f0 = h2f2(us.x), f1 = h2f2(us.y);
        float2 f2 = h2f2(us.z), f3 = h2f2(us.w);
        a[0] = f0.x; a[1] = f0.y; a[2] = f1.x; a[3] = f1.y;
        a[4] = f2.x; a[5] = f2.y; a[6] = f3.x; a[7] = f3.y;
    }
    // prime chunk 0's edge indices (clamped, branch-free)
    int ei = p0 + q;
    ei = min(ei, p1 - 1); ei = max(ei, 0);
    int e = edata[ei];
    #pragma unroll 1
    for (int k8 = 0; k8 < dmax; k8 += 8) {
        int ein = p0 + k8 + 8 + q;
        ein = min(ein, p1 - 1); ein = max(ein, 0);
        int e_nxt = edata[ein];
        uint4 u0[4], u1[4];
        #pragma unroll
        for (int k = 0; k < 4; ++k) u0[k] = ldrow(y, __shfl(e, gbase | k), q);
        #pragma unroll
        for (int k = 0; k < 4; ++k) u1[k] = ldrow(y, __shfl(e, gbase | (4 + k)), q);
        #pragma unroll
        for (int k = 0; k < 4; ++k) acc8(a, u0[k], (k8 + k < deg) ? 1.f : 0.f);
        #pragma unroll
        for (int k = 0; k < 4; ++k) acc8(a, u1[k], (k8 + 4 + k < deg) ? 1.f : 0.f);
        e = e_nxt;
    }
    float dv = rsqrtf((float)deg + 1.f);
    half_t h[8] = { (half_t)(dv * a[0]), (half_t)(dv * a[1]),
                    (half_t)(dv * a[2]), (half_t)(dv * a[3]),
                    (half_t)(dv * a[4]), (half_t)(dv * a[5]),
                    (half_t)(dv * a[6]), (half_t)(dv * a[7]) };
    *(uint4*)&xt[rbase + g][q * 8] = *(uint4*)h;
    __syncthreads();
    // MFMA: wave wv -> row-tile (wv&1), col-tiles (wv>>1)*2 + {0,1}
    int m = lane & 15, q4 = lane >> 4;
    int rt = (wv & 1) * 16;
    int ct0 = (wv >> 1) * 2;
    const half_t* arow = &xt[rt + m][q4 * 8];
    half8 A0 = *(const half8*)arow;
    half8 A1 = *(const half8*)(arow + 32);
    float dvr[4];
    if (!LAST) {
        #pragma unroll
        for (int r = 0; r < 4; ++r) dvr[r] = dinv[n0 + rt + q4 * 4 + r];
    }
    #pragma unroll
    for (int c2 = 0; c2 < 2; ++c2) {
        int ct = (ct0 + c2) * 16;
        const half_t* brow = &Wt[ct + m][q4 * 8];
        half8 B0 = *(const half8*)brow;
        half8 B1 = *(const half8*)(brow + 32);
        f32x4 c = {0.f, 0.f, 0.f, 0.f};
        c = __builtin_amdgcn_mfma_f32_16x16x32_f16(A0, B0, c, 0, 0, 0);
        c = __builtin_amdgcn_mfma_f32_16x16x32_f16(A1, B1, c, 0, 0, 0);
        float bv = bias[ct + m];                   // col = ct*16 + (lane&15)
        #pragma unroll
        for (int r = 0; r < 4; ++r) {
            int row = n0 + rt + q4 * 4 + r;        // C/D: row = quad*4 + reg
            float v = c[r] + bv;
            if (RELU) v = fmaxf(v, 0.f);
            int col = ct + m;
            if (LAST) out_f32[(size_t)row * F + col] = v;
            else      out_h[(size_t)row * F + col] = (half_t)(v * dvr[r]);
        }
    }
}

extern "C" void kernel_launch(void* const* d_in, const int* in_sizes, int n_in,
                              void* d_out, int out_size, void* d_ws, size_t ws_size,
                              hipStream_t stream) {
    const float* X  = (const float*)d_in[0];
    const int*  idx = (const int*)d_in[1];
    const float* W1 = (const float*)d_in[2];
    const float* b1 = (const float*)d_in[3];
    const float* W2 = (const float*)d_in[4];
    const float* b2 = (const float*)d_in[5];
    const float* W3 = (const float*)d_in[6];
    const float* b3 = (const float*)d_in[7];
    float* out = (float*)d_out;

    char* ws = (char*)d_ws;
    int*    bcur    = (int*)(ws);                       // NB ints (1.25 KB)
    int*    row_ptr = (int*)(ws + 4096);                // NN+1 ints
    float*  dinv    = (float*)(ws + 327680);            // NN floats
    int*    edata   = (int*)(ws + 651264);              // NE ints (final CSR)
    half_t* ybufA   = (half_t*)(ws + 5771264);          // [NN,64] fp16
    half_t* ybufB   = (half_t*)(ws + 16011264);         // [NN,64] fp16
    int*    ebuf    = (int*)(ws + 26251264);            // NB*CAP ints (7.7 MB)
    // total ws use ~34 MB

    hipMemsetAsync(bcur, 0, NB * sizeof(int), stream);
    partition_kernel<<<PBLK, 512, 0, stream>>>(idx, bcur, ebuf);
    bucket_sort_kernel<<<NB, 512, 0, stream>>>(bcur, ebuf, X, edata, row_ptr, dinv, ybufA);

    const int fBlocks = NN / 32;      // 2500

    // layer 1: y1 = fp16(dinv*relu(agg(ybufA)@W1+b1)) -> ybufB
    fused_layer<1, 0><<<fBlocks, 256, 0, stream>>>(ybufA, edata, row_ptr, dinv, W1, b1, ybufB, nullptr);
    // layer 2
    fused_layer<1, 0><<<fBlocks, 256, 0, stream>>>(ybufB, edata, row_ptr, dinv, W2, b2, ybufA, nullptr);
    // layer 3: fp32 output, no relu / no scale
    fused_layer<0, 1><<<fBlocks, 256, 0, stream>>>(ybufA, edata, row_ptr, dinv, W3, b3, nullptr, out);
}